// Round 7
// baseline (610.744 us; speedup 1.0000x reference)
//
#include <hip/hip_runtime.h>

#define NN 200000
#define EE 400000
#define GG 4096

// ws layout (float offsets)
#define AGG_OFF 0
#define H1_OFF  (NN * 64)              // 12,800,000
#define SE_OFF  (H1_OFF + NN * 64)     // 25,600,000 (2*GG ints)
#define CHUNK_OFF (SE_OFF + 2 * GG)    // 25,608,192 : hidden-activation buffer (200k x 128)
// CSR arrays live in the UPPER half of cbuf: only gemm n2a (after the last agg
// pass) writes past cbuf+NN*64, so they survive exactly as long as needed.
#define CSR_OFF (CHUNK_OFF + NN * 64)

#define NB1 ((NN + 1023) / 1024)       // 196 scan blocks

// ---------------- segment boundaries from sorted batch ----------------
__global__ void bounds_kernel(const int* __restrict__ batch, int* __restrict__ se) {
    int n = blockIdx.x * blockDim.x + threadIdx.x;
    if (n >= NN) return;
    int b = batch[n];
    if (n == 0 || batch[n - 1] != b) se[b] = n;                 // start
    if (n == NN - 1 || batch[n + 1] != b) se[GG + b] = n + 1;   // end
}

// ---------------- CSR build ----------------
__global__ void deg_kernel(const int* __restrict__ ei, int* __restrict__ cursor) {
    int e = blockIdx.x * blockDim.x + threadIdx.x;
    if (e >= EE) return;
    atomicAdd(cursor + ei[EE + e], 1);
}

// block-level exclusive scan, 1024 elements/block (256 thr x 4)
__global__ __launch_bounds__(256) void scan1_kernel(const int* __restrict__ deg,
                                                    int* __restrict__ rowptr,
                                                    int* __restrict__ partials) {
    __shared__ int sdata[256];
    int t = threadIdx.x;
    int base = blockIdx.x * 1024 + t * 4;
    int v[4]; int s = 0;
#pragma unroll
    for (int j = 0; j < 4; j++) {
        v[j] = (base + j < NN) ? deg[base + j] : 0;
        s += v[j];
    }
    sdata[t] = s;
    __syncthreads();
#pragma unroll
    for (int off = 1; off < 256; off <<= 1) {
        int x = (t >= off) ? sdata[t - off] : 0;
        __syncthreads();
        sdata[t] += x;
        __syncthreads();
    }
    int run = sdata[t] - s;   // exclusive prefix of this thread's chunk
#pragma unroll
    for (int j = 0; j < 4; j++) {
        if (base + j < NN) rowptr[base + j] = run;
        run += v[j];
    }
    if (t == 255) partials[blockIdx.x] = sdata[255];
}

__global__ __launch_bounds__(256) void scan2_kernel(int* __restrict__ partials) {
    __shared__ int sdata[256];
    int t = threadIdx.x;
    int p = (t < NB1) ? partials[t] : 0;
    sdata[t] = p;
    __syncthreads();
#pragma unroll
    for (int off = 1; off < 256; off <<= 1) {
        int x = (t >= off) ? sdata[t - off] : 0;
        __syncthreads();
        sdata[t] += x;
        __syncthreads();
    }
    if (t < NB1) partials[t] = sdata[t] - p;   // exclusive
}

__global__ __launch_bounds__(256) void scan3_kernel(int* __restrict__ rowptr,
                                                    const int* __restrict__ partials) {
    int t = threadIdx.x;
    int add = partials[blockIdx.x];
    int base = blockIdx.x * 1024 + t * 4;
#pragma unroll
    for (int j = 0; j < 4; j++)
        if (base + j < NN) rowptr[base + j] += add;
}

__global__ void scatter_kernel(const int* __restrict__ ei,
                               const int* __restrict__ rowptr,
                               int* __restrict__ cursor,
                               int* __restrict__ eidx) {
    int e = blockIdx.x * blockDim.x + threadIdx.x;
    if (e >= EE) return;
    int d = ei[EE + e];
    int pos = rowptr[d] + atomicAdd(cursor + d, 1);
    eidx[pos] = e;
}

// ---------------- gather aggregation (NO float atomics) ----------------
// wave per node, lane = channel. agg[n] = xin[n] + sum_{e in in(n)} relu(ea[e]@W + b + xin[src[e]])
__global__ __launch_bounds__(256) void agg_pass(const float* __restrict__ xin,
                                                const int* __restrict__ ei,
                                                const float* __restrict__ ea,
                                                const float* __restrict__ ew,
                                                const float* __restrict__ eb,
                                                const int* __restrict__ rowptr,
                                                const int* __restrict__ cnt,
                                                const int* __restrict__ eidx,
                                                float* __restrict__ agg) {
    const int lane = threadIdx.x & 63;
    int n = blockIdx.x * 4 + (threadIdx.x >> 6);
    if (n >= NN) return;   // no barriers in this kernel

    float Wr[16];
#pragma unroll
    for (int k = 0; k < 16; k++) Wr[k] = ew[k * 64 + lane];   // ew: (16,64)
    const float br = eb[lane];

    int s   = __builtin_amdgcn_readfirstlane(rowptr[n]);
    int deg = __builtin_amdgcn_readfirstlane(cnt[n]);

    float sum = xin[(size_t)n * 64 + lane];   // GINE self term (eps=0)

    int ecur = 0;
    if (deg > 0) ecur = __builtin_amdgcn_readfirstlane(eidx[s]);
    for (int i = 0; i < deg; i++) {
        int inext = (i + 1 < deg) ? (i + 1) : i;
        int enext = __builtin_amdgcn_readfirstlane(eidx[s + inext]);
        int src   = __builtin_amdgcn_readfirstlane(ei[ecur]);
        const float4* ea4 = (const float4*)(ea + (size_t)ecur * 16);
        float4 p0 = ea4[0], p1 = ea4[1], p2 = ea4[2], p3 = ea4[3];
        float acc = br;
        acc += p0.x * Wr[0];  acc += p0.y * Wr[1];
        acc += p0.z * Wr[2];  acc += p0.w * Wr[3];
        acc += p1.x * Wr[4];  acc += p1.y * Wr[5];
        acc += p1.z * Wr[6];  acc += p1.w * Wr[7];
        acc += p2.x * Wr[8];  acc += p2.y * Wr[9];
        acc += p2.z * Wr[10]; acc += p2.w * Wr[11];
        acc += p3.x * Wr[12]; acc += p3.y * Wr[13];
        acc += p3.z * Wr[14]; acc += p3.w * Wr[15];
        float xv = xin[(size_t)src * 64 + lane];
        sum += fmaxf(acc + xv, 0.0f);
        ecur = enext;
    }
    agg[(size_t)n * 64 + lane] = sum;
}

// ---------------- tiled dense layer, W staged in LDS (K-chunked), X prefetch ----
template <int K, int C, bool RELU, bool SPLITY>
__global__ __launch_bounds__(256) void gemm_kernel(const float* __restrict__ X,
                                                   const float* __restrict__ W,
                                                   const float* __restrict__ Bv,
                                                   float* __restrict__ Ylo,
                                                   float* __restrict__ Yhi,
                                                   int rows) {
    constexpr int CPT = 8, RPT = 4;
    constexpr int COLG = C / CPT;        // 8 (C=64) or 16 (C=128)
    constexpr int ROWG = 256 / COLG;     // 32 or 16
    constexpr int BR = ROWG * RPT;       // 128 or 64 rows per block
    constexpr int KC = (K < 64) ? K : 64;  // K-chunk staged in LDS (<=32 KB)

    __shared__ float Bs[KC * C];

    const int cg = threadIdx.x % COLG;
    const int rg = threadIdx.x / COLG;
    const int c0a = cg * 4;
    const int c0b = C / 2 + cg * 4;
    const int rbase = blockIdx.x * BR + rg * RPT;

    const float* xptr[RPT];
#pragma unroll
    for (int r = 0; r < RPT; r++) {
        int rr = rbase + r;
        int ri = (rr < rows) ? rr : (rows - 1);
        xptr[r] = X + (size_t)ri * K;
    }

    float acc[RPT][CPT];
    {
        const float4* ba = (const float4*)(Bv + c0a);
        const float4* bb = (const float4*)(Bv + c0b);
        float4 v0 = ba[0], v1 = bb[0];
#pragma unroll
        for (int r = 0; r < RPT; r++) {
            acc[r][0] = v0.x; acc[r][1] = v0.y; acc[r][2] = v0.z; acc[r][3] = v0.w;
            acc[r][4] = v1.x; acc[r][5] = v1.y; acc[r][6] = v1.z; acc[r][7] = v1.w;
        }
    }

    float4 a_cur[RPT], a_nxt[RPT];
#pragma unroll
    for (int r = 0; r < RPT; r++) a_cur[r] = *(const float4*)(xptr[r]);

#pragma unroll 1
    for (int kc = 0; kc < K; kc += KC) {
        __syncthreads();
        {
            const float4* wsrc = (const float4*)(W + (size_t)kc * C);
            float4* wdst = (float4*)Bs;
            for (int i = threadIdx.x; i < KC * C / 4; i += 256) wdst[i] = wsrc[i];
        }
        __syncthreads();

#pragma unroll 2
        for (int k4 = 0; k4 < KC; k4 += 4) {
            const int knext = kc + k4 + 4;
            if (knext < K) {
#pragma unroll
                for (int r = 0; r < RPT; r++)
                    a_nxt[r] = *(const float4*)(xptr[r] + knext);
            }
#pragma unroll
            for (int kk = 0; kk < 4; kk++) {
                const float4 w0 = *(const float4*)(Bs + (k4 + kk) * C + c0a);
                const float4 w1 = *(const float4*)(Bs + (k4 + kk) * C + c0b);
#pragma unroll
                for (int r = 0; r < RPT; r++) {
                    float av = (kk == 0) ? a_cur[r].x : (kk == 1) ? a_cur[r].y
                             : (kk == 2) ? a_cur[r].z : a_cur[r].w;
                    acc[r][0] += av * w0.x; acc[r][1] += av * w0.y;
                    acc[r][2] += av * w0.z; acc[r][3] += av * w0.w;
                    acc[r][4] += av * w1.x; acc[r][5] += av * w1.y;
                    acc[r][6] += av * w1.z; acc[r][7] += av * w1.w;
                }
            }
#pragma unroll
            for (int r = 0; r < RPT; r++) a_cur[r] = a_nxt[r];
        }
    }

#pragma unroll
    for (int r = 0; r < RPT; r++) {
        int rr = rbase + r;
        if (rr < rows) {
            float4 v0, v1;
            v0.x = RELU ? fmaxf(acc[r][0], 0.0f) : acc[r][0];
            v0.y = RELU ? fmaxf(acc[r][1], 0.0f) : acc[r][1];
            v0.z = RELU ? fmaxf(acc[r][2], 0.0f) : acc[r][2];
            v0.w = RELU ? fmaxf(acc[r][3], 0.0f) : acc[r][3];
            v1.x = RELU ? fmaxf(acc[r][4], 0.0f) : acc[r][4];
            v1.y = RELU ? fmaxf(acc[r][5], 0.0f) : acc[r][5];
            v1.z = RELU ? fmaxf(acc[r][6], 0.0f) : acc[r][6];
            v1.w = RELU ? fmaxf(acc[r][7], 0.0f) : acc[r][7];
            if (SPLITY) {
                *(float4*)(Ylo + (size_t)rr * 64 + c0a) = v0;
                *(float4*)(Yhi + (size_t)rr * 64 + (c0b - C / 2)) = v1;
            } else {
                *(float4*)(Ylo + (size_t)rr * C + c0a) = v0;
                *(float4*)(Ylo + (size_t)rr * C + c0b) = v1;
            }
        }
    }
}

// ---------------- head: mean-pool (via segment bounds) + 5-layer MLP ----------------
__global__ __launch_bounds__(128) void head_kernel(const float* __restrict__ hlo,
                                                   const float* __restrict__ hhi,
                                                   const int* __restrict__ se,
                                                   const float* __restrict__ usr,
                                                   const float* __restrict__ h1w, const float* __restrict__ h1b,
                                                   const float* __restrict__ h2w, const float* __restrict__ h2b,
                                                   const float* __restrict__ h3w, const float* __restrict__ h3b,
                                                   const float* __restrict__ h4w, const float* __restrict__ h4b,
                                                   const float* __restrict__ h5w, const float* __restrict__ h5b,
                                                   float* __restrict__ out) {
    int g = blockIdx.x;
    int c = threadIdx.x;
    __shared__ float z0[140];
    __shared__ float z1[128];
    __shared__ float z2[64];
    __shared__ float z3[32];
    __shared__ float z4[16];

    int s = se[g], e = se[GG + g];
    float sum = 0.0f;
    if (c < 64) {
        for (int n = s; n < e; n++) sum += hlo[(size_t)n * 64 + c];
    } else {
        for (int n = s; n < e; n++) sum += hhi[(size_t)n * 64 + (c - 64)];
    }
    float cnt = fmaxf((float)(e - s), 1.0f);
    z0[c] = sum / cnt;
    if (c < 12) z0[128 + c] = usr[g * 12 + c];
    __syncthreads();

    {
        float acc = h1b[c];
        for (int k = 0; k < 140; k++) acc += z0[k] * h1w[k * 128 + c];
        z1[c] = fmaxf(acc, 0.0f);
    }
    __syncthreads();
    if (c < 64) {
        float acc = h2b[c];
        for (int k = 0; k < 128; k++) acc += z1[k] * h2w[k * 64 + c];
        z2[c] = fmaxf(acc, 0.0f);
    }
    __syncthreads();
    if (c < 32) {
        float acc = h3b[c];
        for (int k = 0; k < 64; k++) acc += z2[k] * h3w[k * 32 + c];
        z3[c] = fmaxf(acc, 0.0f);
    }
    __syncthreads();
    if (c < 16) {
        float acc = h4b[c];
        for (int k = 0; k < 32; k++) acc += z3[k] * h4w[k * 16 + c];
        z4[c] = fmaxf(acc, 0.0f);
    }
    __syncthreads();
    if (c == 0) {
        float acc = h5b[0];
        for (int k = 0; k < 16; k++) acc += z4[k] * h5w[k];
        out[g] = acc;
    }
}

extern "C" void kernel_launch(void* const* d_in, const int* in_sizes, int n_in,
                              void* d_out, int out_size, void* d_ws, size_t ws_size,
                              hipStream_t stream) {
    const float* x    = (const float*)d_in[0];
    const int*   ei   = (const int*)d_in[1];
    const float* ea   = (const float*)d_in[2];
    const int*   batch= (const int*)d_in[3];
    const float* usr  = (const float*)d_in[4];
    const float* e1w  = (const float*)d_in[5],  *e1b  = (const float*)d_in[6];
    const float* n1w1 = (const float*)d_in[7],  *n1b1 = (const float*)d_in[8];
    const float* n1w2 = (const float*)d_in[9],  *n1b2 = (const float*)d_in[10];
    const float* e2w  = (const float*)d_in[11], *e2b  = (const float*)d_in[12];
    const float* n2w1 = (const float*)d_in[13], *n2b1 = (const float*)d_in[14];
    const float* n2w2 = (const float*)d_in[15], *n2b2 = (const float*)d_in[16];
    const float* h1w  = (const float*)d_in[17], *h1b  = (const float*)d_in[18];
    const float* h2w  = (const float*)d_in[19], *h2b  = (const float*)d_in[20];
    const float* h3w  = (const float*)d_in[21], *h3b  = (const float*)d_in[22];
    const float* h4w  = (const float*)d_in[23], *h4b  = (const float*)d_in[24];
    const float* h5w  = (const float*)d_in[25], *h5b  = (const float*)d_in[26];

    float* w    = (float*)d_ws;
    float* agg  = w + AGG_OFF;
    float* h1   = w + H1_OFF;
    int*   se   = (int*)(w + SE_OFF);
    float* cbuf = w + CHUNK_OFF;

    int* rowptr   = (int*)(w + CSR_OFF);
    int* cursor   = rowptr + NN;
    int* eidx     = cursor + NN;
    int* partials = eidx + EE;

    hipMemsetAsync(se, 0, (size_t)GG * 2 * sizeof(int), stream);
    hipMemsetAsync(cursor, 0, (size_t)NN * sizeof(int), stream);

    bounds_kernel<<<(NN + 255) / 256, 256, 0, stream>>>(batch, se);

    // ---- CSR build (shared by both layers) ----
    deg_kernel<<<(EE + 255) / 256, 256, 0, stream>>>(ei, cursor);
    scan1_kernel<<<NB1, 256, 0, stream>>>(cursor, rowptr, partials);
    scan2_kernel<<<1, 256, 0, stream>>>(partials);
    scan3_kernel<<<NB1, 256, 0, stream>>>(rowptr, partials);
    hipMemsetAsync(cursor, 0, (size_t)NN * sizeof(int), stream);
    scatter_kernel<<<(EE + 255) / 256, 256, 0, stream>>>(ei, rowptr, cursor, eidx);
    // after scatter, cursor[n] == deg[n]

    // ---- layer 1 ----
    agg_pass<<<(NN + 3) / 4, 256, 0, stream>>>(x, ei, ea, e1w, e1b, rowptr, cursor, eidx, agg);
    gemm_kernel<64, 64, true, false><<<(NN + 127) / 128, 256, 0, stream>>>(
        agg, n1w1, n1b1, cbuf, nullptr, NN);
    gemm_kernel<64, 64, true, false><<<(NN + 127) / 128, 256, 0, stream>>>(
        cbuf, n1w2, n1b2, h1, nullptr, NN);

    // ---- layer 2 ---- (CSR intact: n1a only wrote cbuf[0:NN*64])
    agg_pass<<<(NN + 3) / 4, 256, 0, stream>>>(h1, ei, ea, e2w, e2b, rowptr, cursor, eidx, agg);
    gemm_kernel<64, 128, true, false><<<(NN + 63) / 64, 256, 0, stream>>>(
        agg, n2w1, n2b1, cbuf, nullptr, NN);
    gemm_kernel<128, 128, false, true><<<(NN + 63) / 64, 256, 0, stream>>>(
        cbuf, n2w2, n2b2, agg, h1, NN);

    head_kernel<<<GG, 128, 0, stream>>>(agg, h1, se, usr,
                                        h1w, h1b, h2w, h2b, h3w, h3b, h4w, h4b, h5w, h5b,
                                        (float*)d_out);
}